// Round 8
// baseline (26.476 us; speedup 1.0000x reference)
//
#include <hip/hip_runtime.h>
#include <math.h>

#define NQ 8
#define NL 3
#define NC 3
#define BATCH 16384

// Layout l=6, IDENTITY storage basis: 64 lanes/element (one wave = one elem),
// 4 complex amps per thread. Amp index t[7:0]: bits 0..1 = reg r (wires 0,1),
// bits 2..7 = lane q bits 0..5 (wires 2..7).
// Lazy CNOT frames (verified R5/R7): gate on wire w in frame L^k acts along
// u = L^{-k} e_w with sign row g = row_w(L^k). No CNOT data movement.
// Full 8-bit masks from R7 (verified), re-split as (reg = m&3, lane = m>>2):
//  L rows:   0xFE,0x03,0x07,0x0F,0x1F,0x3F,0x7F,0xFF
//  L^-1 cols:0x03,0x06,0x0C,0x18,0x30,0x60,0xC0,0x83
//  L^2 rows: 0xAB,0xFD,0xFA,0xF5,0xEA,0xD5,0xAA,0x55
//  L^-2 cols:0x05,0x0A,0x14,0x28,0x50,0xA0,0x43,0x86
//  L^3 rows (meas): 0x32,0x56,0xAC
// Exchanges: masks 1..15 DPP (VALU), 16..31 ds_swizzle, >=32 ds_bpermute.

__device__ __forceinline__ int par(int x) { return __popc(x) & 1; }

template<int CTRL>
__device__ __forceinline__ float dppmov(float v) {
  return __builtin_bit_cast(float,
    __builtin_amdgcn_update_dpp(0, __builtin_bit_cast(int, v), CTRL, 0xF, 0xF, true));
}

// exchange with lane (q ^ M) within the 64-lane wave
template<int M>
__device__ __forceinline__ float xl(float v) {
  static_assert(M > 0 && M < 64, "mask range");
  if constexpr (M < 16) {
    constexpr int hi = M & 12;
    constexpr int first = (hi == 0) ? 0 : (hi == 4) ? 0x141    // row_half_mirror = xor7
                          : (hi == 8) ? 0x128                  // row_ror:8      = xor8
                          : 0x140;                             // row_mirror     = xor15
    constexpr int qx = (hi == 4 || hi == 12) ? ((M & 3) ^ 3) : (M & 3);
    constexpr int qc = (qx == 1) ? 0xB1 : (qx == 2) ? 0x4E : 0x1B;
    float t = v;
    if constexpr (first != 0) t = dppmov<first>(t);
    if constexpr (qx != 0)    t = dppmov<qc>(t);
    return t;
  } else if constexpr (M < 32) {
    // within-32-lane xor via ds_swizzle BitMode: offset=(xor<<10)|(or<<5)|and
    return __builtin_bit_cast(float,
      __builtin_amdgcn_ds_swizzle(__builtin_bit_cast(int, v), (M << 10) | 0x1F));
  } else {
    // cross-half xor via full-wave ds_bpermute (addr = (lane^M)*4)
    const int li = (int)(threadIdx.x & 63);
    return __builtin_bit_cast(float,
      __builtin_amdgcn_ds_bpermute(((li ^ M) << 2), __builtin_bit_cast(int, v)));
  }
}

// ---- RY gate templates (byte-identical math to R7's passing kernel) ----

template<int UREG, int GREG, int GLANE>
__device__ __forceinline__ void ry_rr(float (&sr)[4], float (&si)[4],
                                      float c, float s, int q) {
  static_assert((__builtin_popcount(UREG & GREG) & 1) == 1, "<g,u>!=1");
  const float sl = par(q & GLANE) ? s : -s;
  #pragma unroll
  for (int rA = 0; rA < 4; ++rA) {
    if (rA < (rA ^ UREG)) {
      const int rB = rA ^ UREG;
      const float FA = (__builtin_popcount(rA & GREG) & 1) ? -sl : sl;
      const float ar = sr[rA], ai = si[rA];
      sr[rA] = c * ar + FA * sr[rB];
      si[rA] = c * ai + FA * si[rB];
      sr[rB] = c * sr[rB] - FA * ar;
      si[rB] = c * si[rB] - FA * ai;
    }
  }
}

template<int ULANE, int GREG, int GLANE>
__device__ __forceinline__ void ry_ll(float (&sr)[4], float (&si)[4],
                                      float c, float s, int q) {
  static_assert((__builtin_popcount(ULANE & GLANE) & 1) == 1, "<g,u>!=1");
  const float sl = par(q & GLANE) ? s : -s;
  #pragma unroll
  for (int r = 0; r < 4; ++r) {
    const float xr = xl<ULANE>(sr[r]);
    const float xi = xl<ULANE>(si[r]);
    const float F  = (__builtin_popcount(r & GREG) & 1) ? -sl : sl;
    sr[r] = c * sr[r] + F * xr;
    si[r] = c * si[r] + F * xi;
  }
}

template<int UREG, int ULANE, int GREG, int GLANE>
__device__ __forceinline__ void ry_mix(float (&sr)[4], float (&si)[4],
                                       float c, float s, int q) {
  static_assert(((__builtin_popcount(UREG & GREG) + __builtin_popcount(ULANE & GLANE)) & 1) == 1,
                "<g,u>!=1");
  constexpr int RFLIP = __builtin_popcount(GREG & UREG) & 1;
  const float sl = par(q & GLANE) ? s : -s;
  #pragma unroll
  for (int rA = 0; rA < 4; ++rA) {
    if (rA < (rA ^ UREG)) {
      const int rB = rA ^ UREG;
      const float pBr = xl<ULANE>(sr[rB]);
      const float pBi = xl<ULANE>(si[rB]);
      const float pAr = xl<ULANE>(sr[rA]);
      const float pAi = xl<ULANE>(si[rA]);
      const float FA = (__builtin_popcount(rA & GREG) & 1) ? -sl : sl;
      const float FB = RFLIP ? -FA : FA;
      sr[rA] = c * sr[rA] + FA * pBr;
      si[rA] = c * si[rA] + FA * pBi;
      sr[rB] = c * sr[rB] + FB * pAr;
      si[rB] = c * si[rB] + FB * pAi;
    }
  }
}

__global__ __launch_bounds__(256, 6) void vqc_kernel(
    const float* __restrict__ x, const float* __restrict__ qw,
    const float* __restrict__ W, const float* __restrict__ b,
    float* __restrict__ out)
{
  const int tid  = threadIdx.x;
  const int q    = tid & 63;                       // lane = position in element
  const int elem = blockIdx.x * 4 + (tid >> 6);    // one wave per element

  const float PI = 3.14159265358979323846f;

  float xs[8];
  {
    const float4 x0 = *(const float4*)(x + elem * 8);
    const float4 x1 = *(const float4*)(x + elem * 8 + 4);
    xs[0] = x0.x; xs[1] = x0.y; xs[2] = x0.z; xs[3] = x0.w;
    xs[4] = x1.x; xs[5] = x1.y; xs[6] = x1.z; xs[7] = x1.w;
  }

  float sr[4], si[4];

  // ===== layer 0 RY: product state (real), streaming =====
  {
    float c0_, s0_, c1_, s1_;
    __sincosf(0.5f * (PI * xs[0] + qw[0]), &s0_, &c0_);
    __sincosf(0.5f * (PI * xs[1] + qw[1]), &s1_, &c1_);
    float P = 1.f;
    #pragma unroll
    for (int w = 2; w < 8; ++w) {
      float s_, c_;
      __sincosf(0.5f * (PI * xs[w] + qw[w]), &s_, &c_);
      P *= ((q >> (w - 2)) & 1) ? s_ : c_;
    }
    sr[0] = P * c0_ * c1_;
    sr[1] = P * s0_ * c1_;
    sr[2] = P * c0_ * s1_;
    sr[3] = P * s0_ * s1_;
  }

  // ===== lazy CNOT #1 ; RZ layer 0 in frame L (real -> complex) =====
  // rows: h0:(r2,l63)  h1..h7:(r3, l{0,1,3,7,15,31,63})
  {
    const float h0 = 0.5f * qw[8],  h1 = 0.5f * qw[9];
    const float h2 = 0.5f * qw[10], h3 = 0.5f * qw[11];
    const float h4 = 0.5f * qw[12], h5 = 0.5f * qw[13];
    const float h6 = 0.5f * qw[14], h7 = 0.5f * qw[15];
    const float a0 = par(q & 63) ? h0 : -h0;
    const float B  = -h1 + (par(q & 1)  ? h2 : -h2) + (par(q & 3)  ? h3 : -h3)
                         + (par(q & 7)  ? h4 : -h4) + (par(q & 15) ? h5 : -h5)
                         + (par(q & 31) ? h6 : -h6) + (par(q & 63) ? h7 : -h7);
    // phi[r] = sg(r&2)a0 + sg(r&3)B ; phi2=-phi0, phi3=-phi1
    float sp0, cp0, sp1, cp1;
    __sincosf(a0 + B, &sp0, &cp0);
    __sincosf(a0 - B, &sp1, &cp1);
    si[0] =  sp0 * sr[0]; sr[0] *= cp0;
    si[1] =  sp1 * sr[1]; sr[1] *= cp1;
    si[2] = -sp0 * sr[2]; sr[2] *= cp0;
    si[3] = -sp1 * sr[3]; sr[3] *= cp1;
  }

  // ===== layer 1 RY (frame L): u = L^-1 e_w, g = row_w(L) =====
  {
    float c_, s_;
    __sincosf(0.5f * (PI * xs[0] + qw[16]), &s_, &c_); ry_rr <3,     2, 63>(sr, si, c_, s_, q);
    __sincosf(0.5f * (PI * xs[1] + qw[17]), &s_, &c_); ry_mix<2, 1,  3,  0>(sr, si, c_, s_, q);
    __sincosf(0.5f * (PI * xs[2] + qw[18]), &s_, &c_); ry_ll <3,     3,  1>(sr, si, c_, s_, q);
    __sincosf(0.5f * (PI * xs[3] + qw[19]), &s_, &c_); ry_ll <6,     3,  3>(sr, si, c_, s_, q);
    __sincosf(0.5f * (PI * xs[4] + qw[20]), &s_, &c_); ry_ll <12,    3,  7>(sr, si, c_, s_, q);
    __sincosf(0.5f * (PI * xs[5] + qw[21]), &s_, &c_); ry_ll <24,    3, 15>(sr, si, c_, s_, q);
    __sincosf(0.5f * (PI * xs[6] + qw[22]), &s_, &c_); ry_ll <48,    3, 31>(sr, si, c_, s_, q);
    __sincosf(0.5f * (PI * xs[7] + qw[23]), &s_, &c_); ry_mix<3, 32, 3, 63>(sr, si, c_, s_, q);
  }

  // ===== lazy CNOT #2 ; RZ layer 1 in frame L^2 =====
  // groups: t0=h0:(r3,l42); D1(r1): h1:l63,h3:l61,h5:l53,h7:l21;
  //         D2(r2): h2:l62,h4:l58,h6:l42
  {
    const float h0 = 0.5f * qw[24], h1 = 0.5f * qw[25];
    const float h2 = 0.5f * qw[26], h3 = 0.5f * qw[27];
    const float h4 = 0.5f * qw[28], h5 = 0.5f * qw[29];
    const float h6 = 0.5f * qw[30], h7 = 0.5f * qw[31];
    const float t0 = par(q & 42) ? h0 : -h0;
    const float D1 = (par(q & 63) ? h1 : -h1) + (par(q & 61) ? h3 : -h3)
                   + (par(q & 53) ? h5 : -h5) + (par(q & 21) ? h7 : -h7);
    const float D2 = (par(q & 62) ? h2 : -h2) + (par(q & 58) ? h4 : -h4)
                   + (par(q & 42) ? h6 : -h6);
    // phi[r] = sg(r&3)t0 + sg(r&1)D1 + sg(r&2)D2
    const float ph[4] = { t0 + D1 + D2, -t0 - D1 + D2,
                          -t0 + D1 - D2,  t0 - D1 - D2 };
    #pragma unroll
    for (int r = 0; r < 4; ++r) {
      float sp, cp;
      __sincosf(ph[r], &sp, &cp);
      const float re = sr[r], im = si[r];
      sr[r] = cp * re - sp * im;
      si[r] = cp * im + sp * re;
    }
  }

  // ===== layer 2 RY (frame L^2): u = L^-2 e_w, g = row_w(L^2) =====
  {
    float c_, s_;
    __sincosf(0.5f * (PI * xs[0] + qw[32]), &s_, &c_); ry_mix<1, 1,  3, 42>(sr, si, c_, s_, q);
    __sincosf(0.5f * (PI * xs[1] + qw[33]), &s_, &c_); ry_mix<2, 2,  1, 63>(sr, si, c_, s_, q);
    __sincosf(0.5f * (PI * xs[2] + qw[34]), &s_, &c_); ry_ll <5,     2, 62>(sr, si, c_, s_, q);
    __sincosf(0.5f * (PI * xs[3] + qw[35]), &s_, &c_); ry_ll <10,    1, 61>(sr, si, c_, s_, q);
    __sincosf(0.5f * (PI * xs[4] + qw[36]), &s_, &c_); ry_ll <20,    2, 58>(sr, si, c_, s_, q);
    __sincosf(0.5f * (PI * xs[5] + qw[37]), &s_, &c_); ry_ll <40,    1, 53>(sr, si, c_, s_, q);
    __sincosf(0.5f * (PI * xs[6] + qw[38]), &s_, &c_); ry_mix<3, 16, 2, 42>(sr, si, c_, s_, q);
    __sincosf(0.5f * (PI * xs[7] + qw[39]), &s_, &c_); ry_mix<2, 33, 1, 21>(sr, si, c_, s_, q);
  }

  // ===== lazy CNOT #3 ; RZ2 dropped ; measure in frame L^3 =====
  // z0: (r2,l12)  z1: (r2,l21)  z2: (r0,l43)
  const float p0 = sr[0] * sr[0] + si[0] * si[0];
  const float p1 = sr[1] * sr[1] + si[1] * si[1];
  const float p2 = sr[2] * sr[2] + si[2] * si[2];
  const float p3 = sr[3] * sr[3] + si[3] * si[3];
  const float ta = (p0 + p1) - (p2 + p3);   // sg(r&2) partial (shared z0,z1)
  const float tb =  p0 + p1 + p2 + p3;      // reg-independent (z2)
  float z0 = par(q & 12) ? -ta : ta;
  float z1 = par(q & 21) ? -ta : ta;
  float z2 = par(q & 43) ? -tb : tb;

  // 64-lane butterfly (DPP for 1,2,4,8; swizzle 16; bpermute 32)
  z0 += xl<1>(z0);  z1 += xl<1>(z1);  z2 += xl<1>(z2);
  z0 += xl<2>(z0);  z1 += xl<2>(z1);  z2 += xl<2>(z2);
  z0 += xl<4>(z0);  z1 += xl<4>(z1);  z2 += xl<4>(z2);
  z0 += xl<8>(z0);  z1 += xl<8>(z1);  z2 += xl<8>(z2);
  z0 += xl<16>(z0); z1 += xl<16>(z1); z2 += xl<16>(z2);
  z0 += xl<32>(z0); z1 += xl<32>(z1); z2 += xl<32>(z2);

  if (q < NC) {
    out[elem * NC + q] = b[q] + W[q * 3 + 0] * z0 + W[q * 3 + 1] * z1
                              + W[q * 3 + 2] * z2;
  }
}

extern "C" void kernel_launch(void* const* d_in, const int* in_sizes, int n_in,
                              void* d_out, int out_size, void* d_ws, size_t ws_size,
                              hipStream_t stream) {
  const float* x  = (const float*)d_in[0];
  const float* qw = (const float*)d_in[1];
  const float* W  = (const float*)d_in[2];
  const float* b  = (const float*)d_in[3];
  float* out = (float*)d_out;

  dim3 grid(BATCH / 4);   // 4 elements (waves) per 256-thread block
  vqc_kernel<<<grid, 256, 0, stream>>>(x, qw, W, b, out);
}